// Round 6
// baseline (231.300 us; speedup 1.0000x reference)
//
#include <hip/hip_runtime.h>
#include <stdint.h>

#define AS1 __attribute__((address_space(1)))
#define AS3 __attribute__((address_space(3)))

typedef int v4i __attribute__((ext_vector_type(4)));

// Problem constants (from reference)
constexpr int G = 7, B = 8, M = 512, N = 512, K = 1024;
constexpr int GBn = G * B;                       // 56
// X_ZP = -66, Y_ZP = 160.  With y' = y - 128:
//   sum (x-X)(y-Y) = dot_i8(x, y') - 32*rowsum_x + 66*colsum_y' - 2162688

// ws layout
constexpr size_t X8_BYTES = (size_t)GBn * M * K; // 29,360,128  packed x int8
constexpr size_t YT_BYTES = (size_t)B * N * K;   //  4,194,304  y transposed [b][n][k] i8 (y-128)
constexpr size_t RS_CNT   = (size_t)GBn * M;     // 28,672 rowsums
constexpr size_t CS_CNT   = (size_t)B * N;       //  4,096 colsums
constexpr size_t WS_NEEDED = X8_BYTES + YT_BYTES + RS_CNT * 4 + CS_CNT * 4;

// ---------------------------------------------------------------------------
// K1: transpose + pack y:  y[b][k][n] (int32, 0..255)  ->  yt[b][n][k] (int8, y-128)
// ---------------------------------------------------------------------------
__global__ __launch_bounds__(256) void transpose_pack_y(const int* __restrict__ y,
                                                        signed char* __restrict__ yt) {
    __shared__ unsigned char tile[64][80];
    int n0 = blockIdx.x * 64;
    int k0 = blockIdx.y * 64;
    int b  = blockIdx.z;
    int t  = threadIdx.x;

    int r  = t >> 2;
    int c0 = (t & 3) * 16;
    const int* src = y + ((size_t)b * K + k0 + r) * N + n0 + c0;
    uint32_t p[4];
#pragma unroll
    for (int q = 0; q < 4; ++q) {
        int4 v = ((const int4*)src)[q];
        p[q] =  (uint32_t)((v.x & 255) ^ 128)
             | ((uint32_t)((v.y & 255) ^ 128) << 8)
             | ((uint32_t)((v.z & 255) ^ 128) << 16)
             | ((uint32_t)((v.w & 255) ^ 128) << 24);
    }
    *(uint4*)&tile[r][c0] = make_uint4(p[0], p[1], p[2], p[3]);
    __syncthreads();

    int nl = t >> 2;
    int kc = (t & 3) * 16;
    uint32_t q[4];
#pragma unroll
    for (int w = 0; w < 4; ++w) {
        uint32_t b0 = tile[kc + w * 4 + 0][nl];
        uint32_t b1 = tile[kc + w * 4 + 1][nl];
        uint32_t b2 = tile[kc + w * 4 + 2][nl];
        uint32_t b3 = tile[kc + w * 4 + 3][nl];
        q[w] = b0 | (b1 << 8) | (b2 << 16) | (b3 << 24);
    }
    *(uint4*)(yt + ((size_t)b * N + n0 + nl) * K + k0 + kc) = make_uint4(q[0], q[1], q[2], q[3]);
}

// ---------------------------------------------------------------------------
// K2: pack x int32 -> int8 + rowsum(x); plus colsum(y') from yt.
// One wave per 1024-elem row. Grid: 8192 blocks x 256 (4 rows/block).
// ---------------------------------------------------------------------------
__device__ __forceinline__ int wave_reduce_sum(int v) {
#pragma unroll
    for (int off = 32; off > 0; off >>= 1) v += __shfl_down(v, off, 64);
    return v;
}

__global__ __launch_bounds__(256) void pack_x_sums(const int* __restrict__ x,
                                                   signed char* __restrict__ x8,
                                                   const signed char* __restrict__ yt,
                                                   int* __restrict__ rowsum,
                                                   int* __restrict__ colsum) {
    int wave = threadIdx.x >> 6, lane = threadIdx.x & 63;
    int row = blockIdx.x * 4 + wave;
    if (row < (int)(GBn * M)) {
        const int* src = x + (size_t)row * K + lane * 16;
        int s = 0;
        uint32_t p[4];
#pragma unroll
        for (int q = 0; q < 4; ++q) {
            int4 v = ((const int4*)src)[q];
            s += v.x + v.y + v.z + v.w;
            p[q] =  (uint32_t)(v.x & 255)
                 | ((uint32_t)(v.y & 255) << 8)
                 | ((uint32_t)(v.z & 255) << 16)
                 | ((uint32_t)(v.w & 255) << 24);
        }
        *(uint4*)(x8 + (size_t)row * K + lane * 16) = make_uint4(p[0], p[1], p[2], p[3]);
        s = wave_reduce_sum(s);
        if (lane == 0) rowsum[row] = s;
    } else {
        int rr = row - (int)(GBn * M);
        uint4 u = *(const uint4*)(yt + (size_t)rr * K + lane * 16);
        uint32_t wds[4] = {u.x, u.y, u.z, u.w};
        int s = 0;
#pragma unroll
        for (int q = 0; q < 4; ++q) {
            uint32_t w = wds[q];
            s += (int)(signed char)(w) + (int)(signed char)(w >> 8)
               + (int)(signed char)(w >> 16) + (int)(signed char)(w >> 24);
        }
        s = wave_reduce_sum(s);
        if (lane == 0) colsum[rr] = s;
    }
}

// ---------------------------------------------------------------------------
// K3: BARRIER-FREE wave-private i8 MFMA GEMM.
// Each wave owns a 64x64 C-tile and a private 16 KB LDS double-buffer
// ([buf][A 4KB | B 4KB]); no LDS sharing -> zero __syncthreads in the K-loop.
// Per step s:  s_waitcnt vmcnt(8)   (stage(s) landed; stage(s+1)'s 8 stay
//              in flight — never drains to 0 until the last step)
//              8x ds_read_b128 frags; s_waitcnt lgkmcnt(0)
//              issue stage(s+2) into the buffer just read (8 global_load_lds)
//              16x mfma_i32_16x16x64_i8
// LDS slot swizzle (proven bit-exact R3-R5): phys 16B slot p of row r holds
// k-chunk p ^ ((r>>1)&3), staged by permuting each lane's source chunk.
// Block = 4 waves = 128x128 C-tile. Grid: (4,4,56). LDS 64 KB -> 2 blocks/CU.
// ---------------------------------------------------------------------------
__global__ __launch_bounds__(256, 2) void gemm_i8(const signed char* __restrict__ x8,
                                                  const signed char* __restrict__ yt,
                                                  const int* __restrict__ rowsum,
                                                  const int* __restrict__ colsum,
                                                  const float* __restrict__ xsp,
                                                  const float* __restrict__ ysp,
                                                  float* __restrict__ out) {
    __shared__ signed char lds[4][2][8192];   // [wave][buf][A 4096 | B 4096]

    int mt = blockIdx.x, nt = blockIdx.y, gb = blockIdx.z;
    int b  = gb & 7;
    int tid = threadIdx.x, w = tid >> 6, lane = tid & 63;
    int wm = (w >> 1) * 64, wn = (w & 1) * 64;

    // stage source: instr c covers rows c*16 + (lane>>2); lane's chunk swizzled
    int chunk = ((lane & 3) ^ ((lane >> 3) & 3)) * 16;
    const signed char* Ab = x8 + ((size_t)(gb * M + mt * 128 + wm + (lane >> 2))) * K + chunk;
    const signed char* Bb = yt + ((size_t)(b  * N + nt * 128 + wn + (lane >> 2))) * K + chunk;
    signed char* L = &lds[w][0][0];

    int fr = lane & 15, q = lane >> 4;
    int fko = (q ^ ((fr >> 1) & 3)) * 16;     // swizzled 16B slot for frag reads

    v4i acc[4][4];
#pragma unroll
    for (int i = 0; i < 4; ++i)
#pragma unroll
        for (int j = 0; j < 4; ++j) acc[i][j] = (v4i){0, 0, 0, 0};

#define STAGE(SIDX, BUF)                                                                  \
    do {                                                                                  \
        _Pragma("unroll")                                                                 \
        for (int c = 0; c < 4; ++c)                                                       \
            __builtin_amdgcn_global_load_lds(                                             \
                (const AS1 uint32_t*)(Ab + (size_t)c * 16 * K + (SIDX) * 64),             \
                (AS3 uint32_t*)(L + (BUF) * 8192 + c * 1024), 16, 0, 0);                  \
        _Pragma("unroll")                                                                 \
        for (int c = 0; c < 4; ++c)                                                       \
            __builtin_amdgcn_global_load_lds(                                             \
                (const AS1 uint32_t*)(Bb + (size_t)c * 16 * K + (SIDX) * 64),             \
                (AS3 uint32_t*)(L + (BUF) * 8192 + 4096 + c * 1024), 16, 0, 0);           \
    } while (0)

    STAGE(0, 0);
    STAGE(1, 1);

    for (int s = 0; s < 16; ++s) {
        int buf = s & 1;
        if (s < 15) asm volatile("s_waitcnt vmcnt(8)" ::: "memory");
        else        asm volatile("s_waitcnt vmcnt(0)" ::: "memory");

        v4i af[4], bf[4];
#pragma unroll
        for (int i = 0; i < 4; ++i)
            af[i] = *(const v4i*)(L + buf * 8192 + (i * 16 + fr) * 64 + fko);
#pragma unroll
        for (int j = 0; j < 4; ++j)
            bf[j] = *(const v4i*)(L + buf * 8192 + 4096 + (j * 16 + fr) * 64 + fko);
        asm volatile("s_waitcnt lgkmcnt(0)" ::: "memory");   // frags in regs; buf reusable

        if (s < 14) STAGE(s + 2, buf);

#pragma unroll
        for (int i = 0; i < 4; ++i)
#pragma unroll
            for (int j = 0; j < 4; ++j)
                acc[i][j] = __builtin_amdgcn_mfma_i32_16x16x64_i8(af[i], bf[j], acc[i][j], 0, 0, 0);
    }
#undef STAGE

    // epilogue: C = s * (dot - 32*rowsum_x + 66*colsum_y' - 2162688)
    float sc = xsp[0] * ysp[0];
    int colL = lane & 15;
    int rowQ = (lane >> 4) * 4;
    float* outg = out + (size_t)gb * M * N;
    const int* rs = rowsum + gb * M;
    const int* cs = colsum + b * N;
#pragma unroll
    for (int i = 0; i < 4; ++i) {
#pragma unroll
        for (int r = 0; r < 4; ++r) {
            int row_g = mt * 128 + wm + i * 16 + rowQ + r;
            int rsv = rs[row_g];
#pragma unroll
            for (int j = 0; j < 4; ++j) {
                int col_g = nt * 128 + wn + j * 16 + colL;
                int t = acc[i][j][r] - 32 * rsv + 66 * cs[col_g] - 2162688;
                outg[(size_t)row_g * N + col_g] = sc * (float)t;
            }
        }
    }
}

// ---------------------------------------------------------------------------
// Fallback (only if ws_size is too small): naive but correct.
// ---------------------------------------------------------------------------
__global__ __launch_bounds__(256) void naive_kernel(const int* __restrict__ x,
                                                    const int* __restrict__ y,
                                                    const float* __restrict__ xsp,
                                                    const float* __restrict__ ysp,
                                                    float* __restrict__ out) {
    size_t idx = (size_t)blockIdx.x * 256 + threadIdx.x;
    int n  = (int)(idx & 511);
    int m  = (int)((idx >> 9) & 511);
    int gb = (int)(idx >> 18);
    int b  = gb & 7;
    const int* xr = x + ((size_t)gb * M + m) * K;
    const int* yc = y + (size_t)b * K * N + n;
    int dot = 0, sx = 0, sy = 0;
    for (int k = 0; k < K; ++k) {
        int a = xr[k];
        int c = yc[(size_t)k * N];
        dot += a * c; sx += a; sy += c;
    }
    float s = xsp[0] * ysp[0];
    out[idx] = s * (float)(dot - 160 * sx + 66 * sy - 10813440);
}

// ---------------------------------------------------------------------------
extern "C" void kernel_launch(void* const* d_in, const int* in_sizes, int n_in,
                              void* d_out, int out_size, void* d_ws, size_t ws_size,
                              hipStream_t stream) {
    const int*   x  = (const int*)d_in[0];
    const int*   y  = (const int*)d_in[1];
    const float* xs = (const float*)d_in[2];
    const float* ys = (const float*)d_in[3];
    float* out = (float*)d_out;

    if (ws_size < WS_NEEDED) {
        naive_kernel<<<(14680064 + 255) / 256, 256, 0, stream>>>(x, y, xs, ys, out);
        return;
    }

    char* ws = (char*)d_ws;
    signed char* x8 = (signed char*)ws;
    signed char* yt = (signed char*)(ws + X8_BYTES);
    int* rowsum = (int*)(ws + X8_BYTES + YT_BYTES);
    int* colsum = rowsum + RS_CNT;

    transpose_pack_y<<<dim3(N / 64, K / 64, B), 256, 0, stream>>>(y, yt);
    pack_x_sums<<<(GBn * M + CS_CNT) / 4, 256, 0, stream>>>(x, x8, yt, rowsum, colsum);
    gemm_i8<<<dim3(M / 128, N / 128, GBn), 256, 0, stream>>>(x8, yt, rowsum, colsum, xs, ys, out);
}

// Round 7
// 227.794 us; speedup vs baseline: 1.0154x; 1.0154x over previous
//
#include <hip/hip_runtime.h>
#include <stdint.h>

#define AS1 __attribute__((address_space(1)))
#define AS3 __attribute__((address_space(3)))

typedef int v4i __attribute__((ext_vector_type(4)));

// Problem constants (from reference)
constexpr int G = 7, B = 8, M = 512, N = 512, K = 1024;
constexpr int GBn = G * B;                       // 56
// X_ZP = -66, Y_ZP = 160.  With y' = y - 128:
//   sum (x-X)(y-Y) = dot_i8(x, y') - 32*rowsum_x + 66*colsum_y' - 2162688

// ws layout
constexpr size_t X8_BYTES = (size_t)GBn * M * K; // 29,360,128  packed x int8
constexpr size_t YT_BYTES = (size_t)B * N * K;   //  4,194,304  y transposed [b][n][k] i8 (y-128)
constexpr size_t RS_CNT   = (size_t)GBn * M;     // 28,672 rowsums
constexpr size_t CS_CNT   = (size_t)B * N;       //  4,096 colsums
constexpr size_t WS_NEEDED = X8_BYTES + YT_BYTES + RS_CNT * 4 + CS_CNT * 4;

// ---------------------------------------------------------------------------
// K1: transpose + pack y:  y[b][k][n] (int32, 0..255)  ->  yt[b][n][k] (int8, y-128)
// ---------------------------------------------------------------------------
__global__ __launch_bounds__(256) void transpose_pack_y(const int* __restrict__ y,
                                                        signed char* __restrict__ yt) {
    __shared__ unsigned char tile[64][80];
    int n0 = blockIdx.x * 64;
    int k0 = blockIdx.y * 64;
    int b  = blockIdx.z;
    int t  = threadIdx.x;

    int r  = t >> 2;
    int c0 = (t & 3) * 16;
    const int* src = y + ((size_t)b * K + k0 + r) * N + n0 + c0;
    uint32_t p[4];
#pragma unroll
    for (int q = 0; q < 4; ++q) {
        int4 v = ((const int4*)src)[q];
        p[q] =  (uint32_t)((v.x & 255) ^ 128)
             | ((uint32_t)((v.y & 255) ^ 128) << 8)
             | ((uint32_t)((v.z & 255) ^ 128) << 16)
             | ((uint32_t)((v.w & 255) ^ 128) << 24);
    }
    *(uint4*)&tile[r][c0] = make_uint4(p[0], p[1], p[2], p[3]);
    __syncthreads();

    int nl = t >> 2;
    int kc = (t & 3) * 16;
    uint32_t q[4];
#pragma unroll
    for (int w = 0; w < 4; ++w) {
        uint32_t b0 = tile[kc + w * 4 + 0][nl];
        uint32_t b1 = tile[kc + w * 4 + 1][nl];
        uint32_t b2 = tile[kc + w * 4 + 2][nl];
        uint32_t b3 = tile[kc + w * 4 + 3][nl];
        q[w] = b0 | (b1 << 8) | (b2 << 16) | (b3 << 24);
    }
    *(uint4*)(yt + ((size_t)b * N + n0 + nl) * K + k0 + kc) = make_uint4(q[0], q[1], q[2], q[3]);
}

// ---------------------------------------------------------------------------
// K2: pack x int32 -> int8 + rowsum(x); plus colsum(y') from yt.
// One wave per 1024-elem row. Grid: 8192 blocks x 256 (4 rows/block).
// ---------------------------------------------------------------------------
__device__ __forceinline__ int wave_reduce_sum(int v) {
#pragma unroll
    for (int off = 32; off > 0; off >>= 1) v += __shfl_down(v, off, 64);
    return v;
}

__global__ __launch_bounds__(256) void pack_x_sums(const int* __restrict__ x,
                                                   signed char* __restrict__ x8,
                                                   const signed char* __restrict__ yt,
                                                   int* __restrict__ rowsum,
                                                   int* __restrict__ colsum) {
    int wave = threadIdx.x >> 6, lane = threadIdx.x & 63;
    int row = blockIdx.x * 4 + wave;
    if (row < (int)(GBn * M)) {
        const int* src = x + (size_t)row * K + lane * 16;
        int s = 0;
        uint32_t p[4];
#pragma unroll
        for (int q = 0; q < 4; ++q) {
            int4 v = ((const int4*)src)[q];
            s += v.x + v.y + v.z + v.w;
            p[q] =  (uint32_t)(v.x & 255)
                 | ((uint32_t)(v.y & 255) << 8)
                 | ((uint32_t)(v.z & 255) << 16)
                 | ((uint32_t)(v.w & 255) << 24);
        }
        *(uint4*)(x8 + (size_t)row * K + lane * 16) = make_uint4(p[0], p[1], p[2], p[3]);
        s = wave_reduce_sum(s);
        if (lane == 0) rowsum[row] = s;
    } else {
        int rr = row - (int)(GBn * M);
        uint4 u = *(const uint4*)(yt + (size_t)rr * K + lane * 16);
        uint32_t wds[4] = {u.x, u.y, u.z, u.w};
        int s = 0;
#pragma unroll
        for (int q = 0; q < 4; ++q) {
            uint32_t w = wds[q];
            s += (int)(signed char)(w) + (int)(signed char)(w >> 8)
               + (int)(signed char)(w >> 16) + (int)(signed char)(w >> 24);
        }
        s = wave_reduce_sum(s);
        if (lane == 0) colsum[rr] = s;
    }
}

// ---------------------------------------------------------------------------
// K3: i8 MFMA GEMM, 256x256 C-tile (halves staged fetch: 229 -> 114 MB).
// 512 threads = 8 waves, wave-tile 128m x 64n (8x4 of 16x16x64 i8 MFMA).
// BK=64, 16 steps; LDS dbuf [2][A 16K | B 16K] = 64 KB; one barrier/step.
// Stage(s+1) issued AFTER the frag reads (fence keeps order) so the compiler
// can't serialize it via a vmcnt(0)-before-ds_read; it drains at next barrier.
// LDS slot swizzle (bit-exact, R3-R6): phys 16B slot p of row r holds k-chunk
// p ^ ((r>>1)&3); staged by permuting each lane's source chunk.
// Grid: (2, 2, 56) = 224 blocks, 1 block/CU.
// ---------------------------------------------------------------------------
__global__ __launch_bounds__(512, 2) void gemm_i8(const signed char* __restrict__ x8,
                                                  const signed char* __restrict__ yt,
                                                  const int* __restrict__ rowsum,
                                                  const int* __restrict__ colsum,
                                                  const float* __restrict__ xsp,
                                                  const float* __restrict__ ysp,
                                                  float* __restrict__ out) {
    __shared__ signed char lds[2][32768];     // [buf][A 16384 | B 16384]

    int mt = blockIdx.x, nt = blockIdx.y, gb = blockIdx.z;
    int b  = gb & 7;
    int tid = threadIdx.x, w = tid >> 6, lane = tid & 63;
    int wm = (w >> 2) * 128;                  // 0 / 128
    int wn = (w & 3) * 64;                    // 0 / 64 / 128 / 192

    // staging: wave w covers tile rows w*32 + c*16 + (lane>>2), c in {0,1};
    // each lane fetches its swizzled 16B chunk of the row's 64B k-slab.
    int srow  = lane >> 2;
    int chunk = ((lane & 3) ^ ((lane >> 3) & 3)) * 16;
    const signed char* Ab = x8 + ((size_t)(gb * M + mt * 256 + w * 32 + srow)) * K + chunk;
    const signed char* Bb = yt + ((size_t)(b  * N + nt * 256 + w * 32 + srow)) * K + chunk;

    int fr = lane & 15, q = lane >> 4;
    int fko = (q ^ ((fr >> 1) & 3)) * 16;     // swizzled slot for frag reads

    v4i acc[8][4];
#pragma unroll
    for (int i = 0; i < 8; ++i)
#pragma unroll
        for (int j = 0; j < 4; ++j) acc[i][j] = (v4i){0, 0, 0, 0};

#define STAGE(SIDX, BUF)                                                                   \
    do {                                                                                   \
        _Pragma("unroll")                                                                  \
        for (int c = 0; c < 2; ++c) {                                                      \
            __builtin_amdgcn_global_load_lds(                                              \
                (const AS1 uint32_t*)(Ab + (size_t)c * 16 * K + (SIDX) * 64),              \
                (AS3 uint32_t*)(&lds[BUF][0] + w * 2048 + c * 1024), 16, 0, 0);            \
            __builtin_amdgcn_global_load_lds(                                              \
                (const AS1 uint32_t*)(Bb + (size_t)c * 16 * K + (SIDX) * 64),              \
                (AS3 uint32_t*)(&lds[BUF][0] + 16384 + w * 2048 + c * 1024), 16, 0, 0);    \
        }                                                                                  \
    } while (0)

    STAGE(0, 0);

    for (int s = 0; s < 16; ++s) {
        int buf = s & 1;
        __syncthreads();                      // drains stage(s) into lds[buf]

        v4i af[8], bf[4];
#pragma unroll
        for (int i = 0; i < 8; ++i)
            af[i] = *(const v4i*)(&lds[buf][0] + (wm + i * 16 + fr) * 64 + fko);
#pragma unroll
        for (int j = 0; j < 4; ++j)
            bf[j] = *(const v4i*)(&lds[buf][0] + 16384 + (wn + j * 16 + fr) * 64 + fko);

        asm volatile("" ::: "memory");        // keep STAGE after the ds_reads
        if (s < 15) STAGE(s + 1, buf ^ 1);    // flies under the 32 MFMAs

#pragma unroll
        for (int i = 0; i < 8; ++i)
#pragma unroll
            for (int j = 0; j < 4; ++j)
                acc[i][j] = __builtin_amdgcn_mfma_i32_16x16x64_i8(af[i], bf[j], acc[i][j], 0, 0, 0);
    }
#undef STAGE

    // epilogue: C = s * (dot - 32*rowsum_x + 66*colsum_y' - 2162688)
    float sc = xsp[0] * ysp[0];
    int colL = lane & 15;
    int rowQ = (lane >> 4) * 4;
    float* outg = out + (size_t)gb * M * N;
    const int* rs = rowsum + gb * M;
    const int* cs = colsum + b * N;
#pragma unroll
    for (int i = 0; i < 8; ++i) {
#pragma unroll
        for (int r = 0; r < 4; ++r) {
            int row_g = mt * 256 + wm + i * 16 + rowQ + r;
            int rsv = rs[row_g];
#pragma unroll
            for (int j = 0; j < 4; ++j) {
                int col_g = nt * 256 + wn + j * 16 + colL;
                int t = acc[i][j][r] - 32 * rsv + 66 * cs[col_g] - 2162688;
                outg[(size_t)row_g * N + col_g] = sc * (float)t;
            }
        }
    }
}

// ---------------------------------------------------------------------------
// Fallback (only if ws_size is too small): naive but correct.
// ---------------------------------------------------------------------------
__global__ __launch_bounds__(256) void naive_kernel(const int* __restrict__ x,
                                                    const int* __restrict__ y,
                                                    const float* __restrict__ xsp,
                                                    const float* __restrict__ ysp,
                                                    float* __restrict__ out) {
    size_t idx = (size_t)blockIdx.x * 256 + threadIdx.x;
    int n  = (int)(idx & 511);
    int m  = (int)((idx >> 9) & 511);
    int gb = (int)(idx >> 18);
    int b  = gb & 7;
    const int* xr = x + ((size_t)gb * M + m) * K;
    const int* yc = y + (size_t)b * K * N + n;
    int dot = 0, sx = 0, sy = 0;
    for (int k = 0; k < K; ++k) {
        int a = xr[k];
        int c = yc[(size_t)k * N];
        dot += a * c; sx += a; sy += c;
    }
    float s = xsp[0] * ysp[0];
    out[idx] = s * (float)(dot - 160 * sx + 66 * sy - 10813440);
}

// ---------------------------------------------------------------------------
extern "C" void kernel_launch(void* const* d_in, const int* in_sizes, int n_in,
                              void* d_out, int out_size, void* d_ws, size_t ws_size,
                              hipStream_t stream) {
    const int*   x  = (const int*)d_in[0];
    const int*   y  = (const int*)d_in[1];
    const float* xs = (const float*)d_in[2];
    const float* ys = (const float*)d_in[3];
    float* out = (float*)d_out;

    if (ws_size < WS_NEEDED) {
        naive_kernel<<<(14680064 + 255) / 256, 256, 0, stream>>>(x, y, xs, ys, out);
        return;
    }

    char* ws = (char*)d_ws;
    signed char* x8 = (signed char*)ws;
    signed char* yt = (signed char*)(ws + X8_BYTES);
    int* rowsum = (int*)(ws + X8_BYTES + YT_BYTES);
    int* colsum = rowsum + RS_CNT;

    transpose_pack_y<<<dim3(N / 64, K / 64, B), 256, 0, stream>>>(y, yt);
    pack_x_sums<<<(GBn * M + CS_CNT) / 4, 256, 0, stream>>>(x, x8, yt, rowsum, colsum);
    gemm_i8<<<dim3(M / 256, N / 256, GBn), 512, 0, stream>>>(x8, yt, rowsum, colsum, xs, ys, out);
}